// Round 2
// baseline (42.520 us; speedup 1.0000x reference)
//
#include <hip/hip_runtime.h>

// LabPool: out[d,l] = max_n( labmap[l,n] * X[d,n] ), labmap one-hot over l.
// Zeros are always in each group's max -> out[d,l] = max(0, max_{n in group l} X[d,n]).
// All results >= 0 -> uint bit-pattern ordering == float ordering (atomicMax on uints).
//
// 3-kernel plan:
//   A) decode_labels: one-hot labmap [L,N] -> packed uint8 labels [N] in ws (200 KB).
//      Branchless (label = sum l*m), 32 independent loads/thread for max MLP.
//   B) labpool_partial2: stream X (HBM) + labels (L2-hot), LDS atomicMax into
//      per-block [D][L] table, dump table to ws.
//   C) labpool_reduce: max over per-block tables -> d_out (f32).

constexpr int L = 32;
constexpr int D = 64;
constexpr int SLOTS = D * L;        // 2048
constexpr int TI = 200;             // items per block in kernel B -> 1000 blocks
constexpr int LAB_WS_BYTES = 204800; // labels region in ws (aligned past 200000)

__global__ __launch_bounds__(256)
void decode_labels(const float* __restrict__ labmap,
                   unsigned* __restrict__ labu, int N)
{
    const int gid = blockIdx.x * 256 + threadIdx.x;
    const int i0 = gid * 4;
    if (i0 >= N) return;
    float a0 = 0.f, a1 = 0.f, a2 = 0.f, a3 = 0.f;
#pragma unroll
    for (int l = 0; l < L; ++l) {
        const float4 m = *reinterpret_cast<const float4*>(labmap + (size_t)l * N + i0);
        a0 = fmaf((float)l, m.x, a0);
        a1 = fmaf((float)l, m.y, a1);
        a2 = fmaf((float)l, m.z, a2);
        a3 = fmaf((float)l, m.w, a3);
    }
    labu[gid] = (unsigned)a0 | ((unsigned)a1 << 8) | ((unsigned)a2 << 16) | ((unsigned)a3 << 24);
}

__global__ __launch_bounds__(256)
void labpool_partial2(const float* __restrict__ X,
                      const unsigned* __restrict__ labu,
                      unsigned* __restrict__ tables, int N)
{
    __shared__ unsigned sm[SLOTS];
    const int tid = threadIdx.x;
    const int n0 = blockIdx.x * TI;
    constexpr int Vc = TI / 4;       // 50 float4 chunks per row-tile

    for (int i = tid; i < SLOTS; i += 256) sm[i] = 0u;
    __syncthreads();

#pragma unroll 4
    for (int idx = tid; idx < D * Vc; idx += 256) {
        const int d = idx / Vc;
        const int v = idx - d * Vc;
        const float4 x = *reinterpret_cast<const float4*>(X + (size_t)d * N + n0 + 4 * v);
        const unsigned lu = labu[n0 / 4 + v];
        atomicMax(&sm[d * L + (lu & 0xffu)],         __float_as_uint(fmaxf(x.x, 0.f)));
        atomicMax(&sm[d * L + ((lu >> 8) & 0xffu)],  __float_as_uint(fmaxf(x.y, 0.f)));
        atomicMax(&sm[d * L + ((lu >> 16) & 0xffu)], __float_as_uint(fmaxf(x.z, 0.f)));
        atomicMax(&sm[d * L + (lu >> 24)],           __float_as_uint(fmaxf(x.w, 0.f)));
    }
    __syncthreads();

    unsigned* dst = tables + (size_t)blockIdx.x * SLOTS;
    for (int i = tid; i < SLOTS; i += 256) dst[i] = sm[i];
}

__global__ __launch_bounds__(256)
void labpool_reduce(const unsigned* __restrict__ tables, float* __restrict__ out, int nb)
{
    __shared__ unsigned red[8][32];
    const int tid = threadIdx.x;
    const int bq = tid >> 5;
    const int sl = tid & 31;
    const int s0 = blockIdx.x * 32;
    unsigned m = 0u;
    for (int b = bq; b < nb; b += 8) {
        const unsigned v = tables[(size_t)b * SLOTS + s0 + sl];
        m = (v > m) ? v : m;
    }
    red[bq][sl] = m;
    __syncthreads();
    if (bq == 0) {
        unsigned r = red[0][sl];
#pragma unroll
        for (int q = 1; q < 8; ++q) {
            const unsigned v = red[q][sl];
            r = (v > r) ? v : r;
        }
        out[s0 + sl] = __uint_as_float(r);
    }
}

// ---- fallback path (small ws): round-1 fused kernel with global atomics ----
__global__ __launch_bounds__(256)
void labpool_fused_atomic(const float* __restrict__ labmap,
                          const float* __restrict__ X,
                          unsigned* __restrict__ gout, int N)
{
    __shared__ unsigned sm[SLOTS];
    __shared__ unsigned char lab[400];
    const int tid = threadIdx.x;
    const int n0 = blockIdx.x * 400;
    for (int i = tid; i < SLOTS; i += 256) sm[i] = 0u;
    constexpr int V = 100;
    for (int idx = tid; idx < L * V; idx += 256) {
        const int l = idx / V;
        const int v = idx - l * V;
        const float4 m = *reinterpret_cast<const float4*>(labmap + (size_t)l * N + n0 + 4 * v);
        if (m.x > 0.5f) lab[4 * v + 0] = (unsigned char)l;
        if (m.y > 0.5f) lab[4 * v + 1] = (unsigned char)l;
        if (m.z > 0.5f) lab[4 * v + 2] = (unsigned char)l;
        if (m.w > 0.5f) lab[4 * v + 3] = (unsigned char)l;
    }
    __syncthreads();
    for (int idx = tid; idx < D * V; idx += 256) {
        const int d = idx / V;
        const int v = idx - d * V;
        const float4 x = *reinterpret_cast<const float4*>(X + (size_t)d * N + n0 + 4 * v);
        const uchar4 lv = *reinterpret_cast<const uchar4*>(&lab[4 * v]);
        atomicMax(&sm[d * L + lv.x], __float_as_uint(fmaxf(x.x, 0.f)));
        atomicMax(&sm[d * L + lv.y], __float_as_uint(fmaxf(x.y, 0.f)));
        atomicMax(&sm[d * L + lv.z], __float_as_uint(fmaxf(x.z, 0.f)));
        atomicMax(&sm[d * L + lv.w], __float_as_uint(fmaxf(x.w, 0.f)));
    }
    __syncthreads();
    for (int i = tid; i < SLOTS; i += 256) atomicMax(&gout[i], sm[i]);
}

__global__ void zero_out_k(unsigned* p, int n)
{
    const int i = blockIdx.x * 256 + threadIdx.x;
    if (i < n) p[i] = 0u;
}

extern "C" void kernel_launch(void* const* d_in, const int* in_sizes, int n_in,
                              void* d_out, int out_size, void* d_ws, size_t ws_size,
                              hipStream_t stream)
{
    const float* labmap = (const float*)d_in[0];   // [L, N]
    const float* X      = (const float*)d_in[1];   // [D, N]
    const int N = in_sizes[0] / L;                 // 200000
    const int nb = N / TI;                         // 1000

    const size_t need = (size_t)LAB_WS_BYTES + (size_t)nb * SLOTS * sizeof(unsigned);
    if (d_ws && ws_size >= need) {
        unsigned* labu   = (unsigned*)d_ws;                                  // [N/4]
        unsigned* tables = (unsigned*)((char*)d_ws + LAB_WS_BYTES);          // [nb][SLOTS]
        decode_labels<<<(N / 4 + 255) / 256, 256, 0, stream>>>(labmap, labu, N);
        labpool_partial2<<<nb, 256, 0, stream>>>(X, labu, tables, N);
        labpool_reduce<<<SLOTS / 32, 256, 0, stream>>>(tables, (float*)d_out, nb);
    } else {
        unsigned* gout = (unsigned*)d_out;
        zero_out_k<<<(SLOTS + 255) / 256, 256, 0, stream>>>(gout, SLOTS);
        labpool_fused_atomic<<<N / 400, 256, 0, stream>>>(labmap, X, gout, N);
    }
}

// Round 3
// 33.720 us; speedup vs baseline: 1.2610x; 1.2610x over previous
//
#include <hip/hip_runtime.h>

// LabPool: out[d,l] = max_n( labmap[l,n] * X[d,n] ), labmap one-hot over l.
// Zeros always participate -> out[d,l] = max(0, max_{label(n)=l} X[d,n]).
// Non-negative results -> uint bit ordering == float ordering (ds_max_u32).
//
// Main kernel layout: lane = feature d (64 lanes = D), item n wave-uniform.
//  -> label is wave-uniform per atomic: 64 distinct LDS addresses, banks
//     (d*33+lab)%32 = (d+lab)%32 -> 2-way (free), NO same-address serialization.
//  -> X column read from LDS tile stride 65: banks (d+n)%32 -> 2-way (free).
// X staged global->LDS coalesced (float4); labels decoded by one wave per tile
// from 32 coalesced dword row-segments (fmaf sum l*m, exact).

constexpr int L = 32;
constexpr int D = 64;            // == wave size: one wave covers all features
constexpr int TI = 64;           // items/tile; 200000/64 = 3125 tiles exactly
constexpr int NB = 768;          // 3 blocks/CU * 256 CU
constexpr int XS_STRIDE = 65;    // padded X-tile row stride (floats)
constexpr int SM_STRIDE = 33;    // padded table row stride (uints)
constexpr int SM_SIZE = D * SM_STRIDE;  // 2112

__global__ __launch_bounds__(256, 3)
void labpool_main(const float* __restrict__ labmap,
                  const float* __restrict__ X,
                  unsigned* __restrict__ tables, int N, int ntiles)
{
    __shared__ float    Xs[2][D * XS_STRIDE];   // 2 x 16.6 KB
    __shared__ unsigned Ls[2][TI];              // per-item labels
    __shared__ unsigned sm[SM_SIZE];            // 8.4 KB padded max table

    const int tid  = threadIdx.x;
    const int wave = tid >> 6;
    const int lane = tid & 63;

    for (int i = tid; i < SM_SIZE; i += 256) sm[i] = 0u;

    int t = blockIdx.x;

    // Prologue: stage tile t into buffer 0.
    if (t < ntiles) {
        const int n0 = t * TI;
#pragma unroll
        for (int k = 0; k < 4; ++k) {
            const int q = tid + 256 * k;         // 1024 float4 chunks
            const int d = q >> 4, c = q & 15;
            const float4 x = *reinterpret_cast<const float4*>(X + (size_t)d * N + n0 + 4 * c);
            *reinterpret_cast<float4*>(&Xs[0][d * XS_STRIDE + 4 * c]) = x;
        }
        if (wave == 0) {
            float acc = 0.f;
#pragma unroll
            for (int l = 0; l < L; ++l)
                acc = fmaf((float)l, labmap[(size_t)l * N + n0 + lane], acc);
            Ls[0][lane] = (unsigned)acc;
        }
    }
    __syncthreads();

    int cur = 0;
    for (; t < ntiles; t += NB) {
        const int tn = t + NB;
        const bool have_next = (tn < ntiles);

        // ---- issue next tile's global loads first (latency hiding) ----
        float4 xst[4];
        float acc = 0.f;
        if (have_next) {
            const int n0 = tn * TI;
#pragma unroll
            for (int k = 0; k < 4; ++k) {
                const int q = tid + 256 * k;
                const int d = q >> 4, c = q & 15;
                xst[k] = *reinterpret_cast<const float4*>(X + (size_t)d * N + n0 + 4 * c);
            }
            if (wave == (t & 3)) {
#pragma unroll
                for (int l = 0; l < L; ++l)
                    acc = fmaf((float)l, labmap[(size_t)l * N + n0 + lane], acc);
            }
        }

        // ---- consume current tile: 16 items per wave, lane = d ----
        {
            const int laneX = lane * XS_STRIDE;
            const int laneS = lane * SM_STRIDE;
#pragma unroll
            for (int j = 0; j < TI / 4; ++j) {
                const int i = wave * (TI / 4) + j;
                const unsigned lab = Ls[cur][i];        // broadcast read
                const float x = Xs[cur][laneX + i];     // 2-way banks, free
                atomicMax(&sm[laneS + lab], __float_as_uint(fmaxf(x, 0.f)));
            }
        }

        // ---- write staged data into the other buffer ----
        if (have_next) {
            const int nxt = cur ^ 1;
#pragma unroll
            for (int k = 0; k < 4; ++k) {
                const int q = tid + 256 * k;
                const int d = q >> 4, c = q & 15;
                *reinterpret_cast<float4*>(&Xs[nxt][d * XS_STRIDE + 4 * c]) = xst[k];
            }
            if (wave == (t & 3)) Ls[nxt][lane] = (unsigned)acc;
        }
        __syncthreads();
        cur ^= 1;
    }

    unsigned* dst = tables + (size_t)blockIdx.x * SM_SIZE;
    for (int i = tid; i < SM_SIZE; i += 256) dst[i] = sm[i];
}

__global__ __launch_bounds__(256)
void labpool_reduce(const unsigned* __restrict__ tables, float* __restrict__ out, int nb)
{
    // 64 blocks: block = feature d; tid: sl = label, bq = table chunk.
    __shared__ unsigned red[8][32];
    const int tid = threadIdx.x;
    const int bq = tid >> 5, sl = tid & 31;
    const int d = blockIdx.x;
    unsigned m = 0u;
#pragma unroll 8
    for (int b = bq; b < nb; b += 8) {
        const unsigned v = tables[(size_t)b * SM_SIZE + d * SM_STRIDE + sl];
        m = (v > m) ? v : m;
    }
    red[bq][sl] = m;
    __syncthreads();
    if (bq == 0) {
        unsigned r = red[0][sl];
#pragma unroll
        for (int q = 1; q < 8; ++q) {
            const unsigned v = red[q][sl];
            r = (v > r) ? v : r;
        }
        out[d * L + sl] = __uint_as_float(r);
    }
}

// ---- fallback (tiny ws): fused kernel with global atomics ----
__global__ __launch_bounds__(256)
void labpool_fused_atomic(const float* __restrict__ labmap,
                          const float* __restrict__ X,
                          unsigned* __restrict__ gout, int N)
{
    __shared__ unsigned sm2[D * L];
    __shared__ unsigned char lab[400];
    const int tid = threadIdx.x;
    const int n0 = blockIdx.x * 400;
    for (int i = tid; i < D * L; i += 256) sm2[i] = 0u;
    constexpr int V = 100;
    for (int idx = tid; idx < L * V; idx += 256) {
        const int l = idx / V;
        const int v = idx - l * V;
        const float4 m = *reinterpret_cast<const float4*>(labmap + (size_t)l * N + n0 + 4 * v);
        if (m.x > 0.5f) lab[4 * v + 0] = (unsigned char)l;
        if (m.y > 0.5f) lab[4 * v + 1] = (unsigned char)l;
        if (m.z > 0.5f) lab[4 * v + 2] = (unsigned char)l;
        if (m.w > 0.5f) lab[4 * v + 3] = (unsigned char)l;
    }
    __syncthreads();
    for (int idx = tid; idx < D * V; idx += 256) {
        const int d = idx / V;
        const int v = idx - d * V;
        const float4 x = *reinterpret_cast<const float4*>(X + (size_t)d * N + n0 + 4 * v);
        const uchar4 lv = *reinterpret_cast<const uchar4*>(&lab[4 * v]);
        atomicMax(&sm2[d * L + lv.x], __float_as_uint(fmaxf(x.x, 0.f)));
        atomicMax(&sm2[d * L + lv.y], __float_as_uint(fmaxf(x.y, 0.f)));
        atomicMax(&sm2[d * L + lv.z], __float_as_uint(fmaxf(x.z, 0.f)));
        atomicMax(&sm2[d * L + lv.w], __float_as_uint(fmaxf(x.w, 0.f)));
    }
    __syncthreads();
    for (int i = tid; i < D * L; i += 256) atomicMax(&gout[i], sm2[i]);
}

__global__ void zero_out_k(unsigned* p, int n)
{
    const int i = blockIdx.x * 256 + threadIdx.x;
    if (i < n) p[i] = 0u;
}

extern "C" void kernel_launch(void* const* d_in, const int* in_sizes, int n_in,
                              void* d_out, int out_size, void* d_ws, size_t ws_size,
                              hipStream_t stream)
{
    const float* labmap = (const float*)d_in[0];   // [L, N]
    const float* X      = (const float*)d_in[1];   // [D, N]
    const int N = in_sizes[0] / L;                 // 200000
    const int ntiles = N / TI;                     // 3125 (exact)

    const size_t need = (size_t)NB * SM_SIZE * sizeof(unsigned);  // ~6.5 MB
    if (d_ws && ws_size >= need && (N % TI) == 0) {
        unsigned* tables = (unsigned*)d_ws;
        labpool_main<<<NB, 256, 0, stream>>>(labmap, X, tables, N, ntiles);
        labpool_reduce<<<D, 256, 0, stream>>>(tables, (float*)d_out, NB);
    } else {
        unsigned* gout = (unsigned*)d_out;
        zero_out_k<<<(D * L + 255) / 256, 256, 0, stream>>>(gout, D * L);
        labpool_fused_atomic<<<N / 400, 256, 0, stream>>>(labmap, X, gout, N);
    }
}